// Round 6
// baseline (477.623 us; speedup 1.0000x reference)
//
#include <hip/hip_runtime.h>
#include <hip/hip_fp16.h>
#include <hip/hip_cooperative_groups.h>

namespace cg = cooperative_groups;

// GCN 2-layer. ONE cooperative front kernel (zero-deg -> count -> scan ->
// bsum-prefix -> fix||fill||gemm1, grid.sync between phases) -> fused
// agg128+gemm2 -> agg64.  7 launches -> 3.
// out[i] = dis[i]*(scaled[i] + sum_j scaled[j]) + b, scaled[j]=dis[j]*(x@W)[j]
//
// r18: gap-hypothesis test. r15..r17 each removed a dispatch+work and bought
// only 1-4us; per-kernel models sum to ~110-140us vs 199 measured, and all
// our kernels are <43us (below the poison fills in top-5). Either dispatch
// boundaries/drains cost ~60us total, or the models are optimistic. This
// round removes 4 boundaries at once (coop kernel, 4 grid.syncs) while
// keeping the latency-bound gather kernels as normal oversubscribed
// launches (coop co-residency would cap their occupancy).
// History: r7 weighted-CSR int2 -11us (reverted); r9 one-block scan 133us
// (reverted); r11 degree-bucket perm: atomic-contention disaster; r12 =
// shfl scan + fix||gemm1 (203us); r13/r14 sliced agg 264us (FALSIFIED:
// gather cost ~ unique lines touched, tier-independent); r15 = +fill fused
// (202us, neutral); r16/r17 = +agg128+gemm2 fused (199us, -3).

typedef _Float16 half8 __attribute__((ext_vector_type(8)));
typedef float floatx4 __attribute__((ext_vector_type(4)));

// ---- shared GEMM helpers (B = W[128|64 x N] staged to LDS, XOR-swizzled) --
// LDS Wt[n][k] fp16 as half2 dwords; 16B block (n,kblk) at dword
// n*64 + (kblk ^ (n&15))*4 (<=2-way banks on b128 reads).
// Frags (m89/m118/m120): A[m=lane&15][k=quad*8+j], B[k=quad*8+j][n=lane&15],
// D row=quad*4+reg, col=lane&15.
template <int N>
__device__ __forceinline__ void stage_w(const float* __restrict__ W,
                                        __half2* wt, int tid) {
    for (int i = tid; i < N * 64; i += 256) {
        int nn = i & (N - 1);
        int k2 = i / N;  // k = 2*k2
        float w0 = W[(size_t)(2 * k2) * N + nn];
        float w1 = W[(size_t)(2 * k2 + 1) * N + nn];
        wt[nn * 64 + ((k2 >> 2) ^ (nn & 15)) * 4 + (k2 & 3)] = __floats2half2_rn(w0, w1);
    }
}

// One 64-row tile of Y[M,N](fp16) = (X[M,128] @ W) * scale[m]; wt pre-staged.
__device__ __forceinline__ void tile128(const float* __restrict__ X,
                                        const float* __restrict__ scale,
                                        __half* __restrict__ Y, int M,
                                        int m0, const __half2* wt, int tid) {
    int wid = tid >> 6, lane = tid & 63;
    int col = lane & 15, quad = lane >> 4;
    int m_a = m0 + wid * 16 + col;
    bool a_ok = m_a < M;
    floatx4 acc[8] = {};
#pragma unroll
    for (int ks = 0; ks < 4; ++ks) {
        int k = ks * 32 + quad * 8;
        floatx4 a0 = {0.f, 0.f, 0.f, 0.f}, a1 = {0.f, 0.f, 0.f, 0.f};
        if (a_ok) {
            a0 = *(const floatx4*)&X[(size_t)m_a * 128 + k];
            a1 = *(const floatx4*)&X[(size_t)m_a * 128 + k + 4];
        }
        half8 af = half8{(_Float16)a0[0], (_Float16)a0[1], (_Float16)a0[2], (_Float16)a0[3],
                         (_Float16)a1[0], (_Float16)a1[1], (_Float16)a1[2], (_Float16)a1[3]};
        int kblk = ks * 4 + quad;
#pragma unroll
        for (int nt = 0; nt < 8; ++nt) {
            int nn = nt * 16 + col;
            half8 bf = *(const half8*)(const void*)&wt[nn * 64 + (kblk ^ (nn & 15)) * 4];
            acc[nt] = __builtin_amdgcn_mfma_f32_16x16x32_f16(af, bf, acc[nt], 0, 0, 0);
        }
    }
    int mbase = m0 + wid * 16 + quad * 4;
    float s[4];
#pragma unroll
    for (int r = 0; r < 4; ++r) s[r] = (mbase + r < M) ? scale[mbase + r] : 0.f;
#pragma unroll
    for (int nt = 0; nt < 8; ++nt) {
#pragma unroll
        for (int r = 0; r < 4; ++r) {
            if (mbase + r < M)
                Y[(size_t)(mbase + r) * 128 + nt * 16 + col] = __float2half(acc[nt][r] * s[r]);
        }
    }
}

// ---- cooperative front kernel -------------------------------------------
// P0 zero deg | P1 count (atomics, writes rank) | P2 per-chunk scan (praw,
// bsum, dis) | P3 bsum exclusive prefix (qpre) | P4 fix rowptr || CSR fill
// || gemm1 (W1 staged once per block, ~4 tiles each).
__global__ __launch_bounds__(256, 4) void k_coop(int* __restrict__ rowptr,
                                                 int* __restrict__ praw,
                                                 int* __restrict__ bsum,
                                                 int* __restrict__ qpre,
                                                 int* __restrict__ deg,
                                                 float* __restrict__ dis,
                                                 int* __restrict__ rank,
                                                 int* __restrict__ csr,
                                                 const float* __restrict__ x,
                                                 const float* __restrict__ W1,
                                                 __half* __restrict__ xw1,
                                                 const int* __restrict__ row,
                                                 const int* __restrict__ col,
                                                 int n, int E, int NCH) {
    __shared__ __align__(16) __half2 wt[128 * 64];  // 32 KB: gemm B / fill q-stage
    __shared__ int wsum[4];
    cg::grid_group grid = cg::this_grid();
    int b = blockIdx.x, tid = threadIdx.x;
    int G = gridDim.x;
    int gid = b * 256 + tid, gsz = G * 256;
    int lane = tid & 63, w = tid >> 6;

    // P0: zero deg
    for (int i = gid; i < n; i += gsz) deg[i] = 0;
    grid.sync();

    // P1: count + rank
    for (int e = gid; e < E; e += gsz) rank[e] = atomicAdd(&deg[col[e]], 1);
    grid.sync();

    // P2: per-chunk scan (1024 elems/chunk, 4/thread) + dis = rsqrt(deg+1)
    if (b < NCH) {
        int i0 = b * 1024 + tid * 4;
        int lv[4], tsum = 0;
        float dv[4];
#pragma unroll
        for (int r = 0; r < 4; ++r) {
            int idx = i0 + r;
            int d = (idx < n) ? deg[idx] : 0;
            tsum += d;
            lv[r] = tsum;
            dv[r] = rsqrtf((float)d + 1.0f);
        }
        int sc = tsum;
#pragma unroll
        for (int off = 1; off < 64; off <<= 1) {
            int t = __shfl_up(sc, off);
            if (lane >= off) sc += t;
        }
        if (lane == 63) wsum[w] = sc;
        __syncthreads();
        int wpre = 0;
#pragma unroll
        for (int j = 0; j < 4; ++j)
            if (j < w) wpre += wsum[j];
        int texcl = wpre + sc - tsum;  // exclusive prefix for this thread
#pragma unroll
        for (int r = 0; r < 4; ++r) {
            int idx = i0 + r;
            if (idx < n) {
                praw[idx + 1] = texcl + lv[r];
                dis[idx] = dv[r];
            }
        }
        if (tid == 255) bsum[b] = wpre + sc;  // block total
    }
    grid.sync();

    // P3: exclusive prefix of bsum -> qpre[0..63]
    if (b == 0) {
        if (tid < 64) {
            int val = (tid < NCH) ? bsum[tid] : 0;
            int s = val;
#pragma unroll
            for (int off = 1; off < 64; off <<= 1) {
                int t = __shfl_up(s, off);
                if ((tid & 63) >= off) s += t;
            }
            qpre[tid] = s - val;
        }
        if (tid == 0) praw[0] = 0;
    }
    grid.sync();

    // P4: three ranges. FIXB=G/16, GEMB=3G/16, FILLB=rest.
    int FIXB = G >> 4;
    int GEMB = (3 * G) >> 4;
    int FILLB = G - FIXB - GEMB;
    if (b < FIXB) {
        for (int j = b * 256 + tid; j <= n; j += FIXB * 256)
            rowptr[j] = (j == 0) ? 0 : praw[j] + qpre[(j - 1) >> 10];
    } else if (b < FIXB + FILLB) {
        int* qlds = (int*)wt;
        if (tid < 64) qlds[tid] = qpre[tid];
        __syncthreads();
        int bb = b - FIXB;
        for (int e = bb * 256 + tid; e < E; e += FILLB * 256) {
            int c = col[e];
            int q0 = (c == 0) ? 0 : qlds[(c - 1) >> 10];
            csr[praw[c] + q0 + rank[e]] = row[e];
        }
    } else {
        stage_w<128>(W1, wt, tid);
        __syncthreads();
        int NT1 = (n + 63) >> 6;
        for (int t = b - FIXB - FILLB; t < NT1; t += GEMB)
            tile128(x, dis, xw1, n, t * 64, wt, tid);
    }
}

// ---- fused agg128 + gemm2 (unchanged from r17) ---------------------------
// Block = 64 nodes (4 agg sub-phases of 16), then xw2[64,64] =
// (h_tile @ W2) * dis via MFMA. h_tile rows XOR-swizzled (slot^=(m&7)).
__global__ __launch_bounds__(256) void k_agg_gemm(const __half* __restrict__ xw,
                                                  const float* __restrict__ dis,
                                                  const int* __restrict__ rowptr,
                                                  const int* __restrict__ csr,
                                                  const float* __restrict__ bias,
                                                  const float* __restrict__ W2,
                                                  __half* __restrict__ Y,  // xw2 [n,64]
                                                  int n) {
    __shared__ __align__(16) half8 htile[64 * 16];   // 16 KB
    __shared__ __align__(16) __half2 wt[64 * 64];    // 16 KB
    int tid = threadIdx.x, b = blockIdx.x;
    int lane = tid & 63, w = tid >> 6;
    int q = lane >> 4, li = lane & 15;
    int qbase = lane & 48;

    // Stage W2 -> LDS (overlaps the first agg phase's latency).
    for (int i = tid; i < 64 * 64; i += 256) {
        int nn = i & 63;
        int k2 = i >> 6;  // k = 2*k2
        float w0 = W2[(size_t)(2 * k2) * 64 + nn];
        float w1 = W2[(size_t)(2 * k2 + 1) * 64 + nn];
        wt[nn * 64 + ((k2 >> 2) ^ (nn & 15)) * 4 + (k2 & 3)] = __floats2half2_rn(w0, w1);
    }

    const half8* rows = (const half8*)xw;  // 16 half8 per row
    floatx4 bb0 = *(const floatx4*)&bias[li * 8];
    floatx4 bb1 = *(const floatx4*)&bias[li * 8 + 4];

#pragma unroll
    for (int g = 0; g < 4; ++g) {
        int m_loc = g * 16 + (w << 2) + q;     // local row 0..63
        int node = b * 64 + m_loc;
        bool ok = node < n;
        float di = 0.f;
        int beg = 0, end = 0;
        if (ok) {
            di = dis[node];
            beg = rowptr[node];
            end = rowptr[node + 1];
        }
        int dg = end - beg;
        int m1 = max(dg, __shfl(dg, lane ^ 16));
        int mx = max(m1, __shfl(m1, lane ^ 32));  // max over the wave's 4 nodes
        float acc[8] = {};
        if (ok) {
            half8 sf = rows[(size_t)node * 16 + li];
#pragma unroll
            for (int f = 0; f < 8; ++f) acc[f] = (float)sf[f];
        }
        for (int i = 0; i < mx; i += 8) {
            int e = beg + i + (li & 7);
            int myidx = (e < end) ? csr[e] : 0;  // one VMEM instr per 8 edges
            half8 v[8];
#pragma unroll
            for (int j = 0; j < 8; ++j) {
                int s = __shfl(myidx, qbase + j);
                v[j] = rows[(size_t)s * 16 + li];
            }
#pragma unroll
            for (int j = 0; j < 8; ++j) {
                if (beg + i + j < end) {
#pragma unroll
                    for (int f = 0; f < 8; ++f) acc[f] += (float)v[j][f];
                }
            }
        }
        half8 o = {};
        if (ok) {
#pragma unroll
            for (int f = 0; f < 4; ++f) o[f] = (_Float16)fmaxf(acc[f] * di + bb0[f], 0.f);
#pragma unroll
            for (int f = 0; f < 4; ++f) o[4 + f] = (_Float16)fmaxf(acc[4 + f] * di + bb1[f], 0.f);
        }
        htile[m_loc * 16 + (li ^ (m_loc & 7))] = o;
    }
    __syncthreads();

    // GEMM phase: A from htile (swizzled), B from wt.
    int col16 = lane & 15, quad = lane >> 4;
    int m_loc = w * 16 + col16;
    floatx4 gacc[4] = {};
#pragma unroll
    for (int ks = 0; ks < 4; ++ks) {
        half8 af = htile[m_loc * 16 + ((ks * 4 + quad) ^ (m_loc & 7))];
        int kblk = ks * 4 + quad;
#pragma unroll
        for (int nt = 0; nt < 4; ++nt) {
            int nn = nt * 16 + col16;
            half8 bf = *(const half8*)(const void*)&wt[nn * 64 + (kblk ^ (nn & 15)) * 4];
            gacc[nt] = __builtin_amdgcn_mfma_f32_16x16x32_f16(af, bf, gacc[nt], 0, 0, 0);
        }
    }
    int mbase = b * 64 + w * 16 + quad * 4;
    float s[4];
#pragma unroll
    for (int r = 0; r < 4; ++r) s[r] = (mbase + r < n) ? dis[mbase + r] : 0.f;
#pragma unroll
    for (int nt = 0; nt < 4; ++nt) {
#pragma unroll
        for (int r = 0; r < 4; ++r) {
            if (mbase + r < n)
                Y[(size_t)(mbase + r) * 64 + nt * 16 + col16] = __float2half(gacc[nt][r] * s[r]);
        }
    }
}

// F=64: 8 nodes/wave (8 lanes x 16B = one 128B row per gather instr).
__global__ __launch_bounds__(256) void k_agg64(const __half* __restrict__ xw,
                                               const float* __restrict__ dis,
                                               const int* __restrict__ rowptr,
                                               const int* __restrict__ csr,
                                               const float* __restrict__ bias,
                                               float* __restrict__ out, int n) {
    int tid = threadIdx.x;
    int lane = tid & 63;
    int o8 = lane >> 3, li = lane & 7;
    int obase = lane & 56;
    int node = blockIdx.x * 32 + ((tid >> 6) << 3) + o8;
    bool ok = node < n;
    float di = 0.f;
    int beg = 0, end = 0;
    if (ok) {
        di = dis[node];
        beg = rowptr[node];
        end = rowptr[node + 1];
    }
    int dg = end - beg;
    int m1 = max(dg, __shfl(dg, lane ^ 8));
    int m2 = max(m1, __shfl(m1, lane ^ 16));
    int mx = max(m2, __shfl(m2, lane ^ 32));  // max over the wave's 8 nodes
    const half8* rows = (const half8*)xw;     // 8 half8 per row
    float acc[8] = {};
    if (ok) {
        half8 sf = rows[(size_t)node * 8 + li];
#pragma unroll
        for (int f = 0; f < 8; ++f) acc[f] = (float)sf[f];
    }
    for (int i = 0; i < mx; i += 8) {
        int e = beg + i + li;
        int myidx = (e < end) ? csr[e] : 0;  // one VMEM instr per 8 edges
        half8 v[8];
#pragma unroll
        for (int j = 0; j < 8; ++j) {
            int s = __shfl(myidx, obase + j);
            v[j] = rows[(size_t)s * 8 + li];
        }
#pragma unroll
        for (int j = 0; j < 8; ++j) {
            if (beg + i + j < end) {
#pragma unroll
                for (int f = 0; f < 8; ++f) acc[f] += (float)v[j][f];
            }
        }
    }
    if (ok) {
        floatx4 b0 = *(const floatx4*)&bias[li * 8];
        floatx4 b1 = *(const floatx4*)&bias[li * 8 + 4];
        floatx4 o0, o1;
#pragma unroll
        for (int f = 0; f < 4; ++f) o0[f] = acc[f] * di + b0[f];
#pragma unroll
        for (int f = 0; f < 4; ++f) o1[f] = acc[4 + f] * di + b1[f];
        *(floatx4*)&out[(size_t)node * 64 + li * 8] = o0;
        *(floatx4*)&out[(size_t)node * 64 + li * 8 + 4] = o1;
    }
}

extern "C" void kernel_launch(void* const* d_in, const int* in_sizes, int n_in,
                              void* d_out, int out_size, void* d_ws, size_t ws_size,
                              hipStream_t stream) {
    const float* x  = (const float*)d_in[0];
    const int*   ei = (const int*)d_in[1];
    const float* W1 = (const float*)d_in[2];
    const float* b1 = (const float*)d_in[3];
    const float* W2 = (const float*)d_in[4];
    const float* b2 = (const float*)d_in[5];
    float* out = (float*)d_out;

    int n = in_sizes[0] / 128;   // 50000
    int E = in_sizes[1] / 2;     // 800000
    const int* row = ei;
    const int* col = ei + E;
    int NCH = (n + 1023) / 1024;       // scan chunks (49)
    const int GB = (n + 63) / 64;      // agg_gemm blocks (782)

    char* ws = (char*)d_ws;
    size_t off = 0;
    auto alloc = [&](size_t bytes) -> void* {
        void* p = ws + off;
        off += (bytes + 255) & ~(size_t)255;
        return p;
    };
    int*    deg    = (int*)alloc((size_t)n * 4);
    int*    rowptr = (int*)alloc((size_t)(n + 1) * 4);
    int*    praw   = (int*)alloc((size_t)(n + 1) * 4);
    int*    bsum   = (int*)alloc((size_t)64 * 4);
    int*    qpre   = (int*)alloc((size_t)64 * 4);
    int*    rank   = (int*)alloc((size_t)E * 4);
    int*    csr    = (int*)alloc((size_t)E * 4);
    float*  dis    = (float*)alloc((size_t)n * 4);
    __half* xw1    = (__half*)alloc((size_t)n * 128 * 2);
    __half* xw2    = (__half*)alloc((size_t)n * 64 * 2);
    (void)ws_size;

    // Cooperative grid size: design target 1024 (4 blocks/CU via
    // __launch_bounds__(256,4), 32KB LDS -> 4/CU); clamp by the runtime's
    // actual occupancy so hipLaunchCooperativeKernel can never over-subscribe.
    int G = 1024;
    int maxb = 0;
    if (hipOccupancyMaxActiveBlocksPerMultiprocessor(&maxb, k_coop, 256, 0) == hipSuccess &&
        maxb > 0) {
        int cap = maxb * 256;  // 256 CUs on MI355X
        if (G > cap) G = cap;
    }
    if (G < 64) G = 64;  // floor: scan needs NCH=49 blocks

    void* cargs[] = {&rowptr, &praw, &bsum, &qpre, &deg, &dis, &rank, &csr,
                     (void*)&x, (void*)&W1, &xw1, (void*)&row, (void*)&col,
                     &n, &E, &NCH};
    hipLaunchCooperativeKernel((const void*)k_coop, dim3(G), dim3(256), cargs, 0, stream);

    // agg128 + gemm2 fused: h never touches HBM.
    k_agg_gemm<<<GB, 256, 0, stream>>>(xw1, dis, rowptr, csr, b1, W2, xw2, n);
    k_agg64<<<(n + 31) / 32, 256, 0, stream>>>(xw2, dis, rowptr, csr, b2, out, n);
}

// Round 7
// 200.732 us; speedup vs baseline: 2.3794x; 2.3794x over previous
//
#include <hip/hip_runtime.h>
#include <hip/hip_fp16.h>

// GCN 2-layer. count (+rank) -> multi-block shfl-scan (fused rsqrt) ->
// [fused scan_fix || MFMA gemm1 || CSR fill] -> [fused agg128+gemm2] -> agg64.
// out[i] = dis[i]*(scaled[i] + sum_j scaled[j]) + b, scaled[j]=dis[j]*(x@W)[j]
//
// r19: r17 structure (198.8us, best) + csr-index software pipelining in the
// gather loops (issue iter i+1's csr load before consuming iter i's rows).
// This tests latency-exposure of the gather: the per-iter chain was
// [load csr -> wait -> shfl -> 8 row loads -> wait -> acc] = 2 serial
// latencies per 8 edges. If the 6.4cy/line constant (r14) was latency not
// line-throughput, this buys 5-10us; if neutral, the line-floor model is
// confirmed and we're at the practical floor.
// r18 POST-MORTEM: cooperative grid.sync() costs ~100us each on 8-XCD
// MI355X (k_coop 492us, VALUBusy 0.6%) — never use coop launch here.
// Dependency audit: dis (scan) must pre-scale xw1 (else agg needs a
// per-edge dis gather, +800K lines), so count->scan->{gemm1||fill} is
// dependency-optimal; no further cross-stage overlap exists.
// History: r7 weighted-CSR int2 -11us (reverted); r9 one-block scan 133us
// (reverted); r11 degree-bucket perm: atomic-contention disaster; r12 =
// shfl scan + fix||gemm1 (203us); r13/r14 sliced agg 264us (FALSIFIED:
// gather cost ~ unique lines touched, tier-independent); r15 = +fill fused
// (202us, neutral); r16/r17 = +agg128+gemm2 fused (199us, -3).

typedef _Float16 half8 __attribute__((ext_vector_type(8)));
typedef float floatx4 __attribute__((ext_vector_type(4)));

__global__ void k_count(const int* __restrict__ col, int* __restrict__ deg,
                        int* __restrict__ rank, int E) {
    int e = blockIdx.x * blockDim.x + threadIdx.x;
    if (e < E) rank[e] = atomicAdd(&deg[col[e]], 1);
}

// Per-chunk inclusive scan via wave shfl (2 barriers) + dis = rsqrt(deg+1).
// Writes rowptr (to be globally fixed) AND praw (raw copy for the fused
// fill, which applies the chunk prefix itself).
__global__ __launch_bounds__(1024) void k_scan_local(const int* __restrict__ deg,
                                                     int* __restrict__ rowptr,
                                                     int* __restrict__ praw,
                                                     int* __restrict__ bsum,
                                                     float* __restrict__ dis, int n) {
    __shared__ int wsum[16];
    int b = blockIdx.x, tid = threadIdx.x;
    int lane = tid & 63, w = tid >> 6;
    int i = b * 1024 + tid;
    int v = (i < n) ? deg[i] : 0;
    if (i < n) dis[i] = rsqrtf((float)v + 1.0f);  // +1 = self-loop
    int sc = v;
#pragma unroll
    for (int off = 1; off < 64; off <<= 1) {
        int t = __shfl_up(sc, off);
        if (lane >= off) sc += t;
    }
    if (lane == 63) wsum[w] = sc;
    __syncthreads();
    if (w == 0) {
        int s = (lane < 16) ? wsum[lane] : 0;
#pragma unroll
        for (int off = 1; off < 16; off <<= 1) {
            int t = __shfl_up(s, off);
            if (lane >= off) s += t;
        }
        if (lane < 16) wsum[lane] = s;
    }
    __syncthreads();
    int incl = sc + ((w > 0) ? wsum[w - 1] : 0);
    if (i < n) {
        rowptr[i + 1] = incl;
        praw[i + 1] = incl;
    }
    if (tid == 1023) bsum[b] = incl;
    if (b == 0 && tid == 0) {
        rowptr[0] = 0;
        praw[0] = 0;
    }
}

// Y[M,N](fp16) = (X[M,128] @ W[128,N]) * scale[m].
// Block: 64 rows (4 waves x 16), all N cols. K=128 in 4 MFMA steps of 32.
// LDS Wt[n][k] fp16 as half2 dwords; 16B block (n,kblk) at dword
// n*64 + (kblk ^ (n&15))*4 (XOR swizzle -> <=2-way banks on b128 reads).
// Frags (m89/m118/m120): A[m=lane&15][k=quad*8+j], B[k=quad*8+j][n=lane&15],
// D row=quad*4+reg, col=lane&15.
template <int N, typename AT>
__device__ __forceinline__ void gemm_tile(const AT* __restrict__ X,
                                          const float* __restrict__ W,
                                          const float* __restrict__ scale,
                                          __half* __restrict__ Y, int M,
                                          int m0, __half2* wt, int tid) {
    for (int i = tid; i < N * 64; i += 256) {
        int nn = i & (N - 1);
        int k2 = i / N;  // k = 2*k2
        float w0 = W[(size_t)(2 * k2) * N + nn];
        float w1 = W[(size_t)(2 * k2 + 1) * N + nn];
        wt[nn * 64 + ((k2 >> 2) ^ (nn & 15)) * 4 + (k2 & 3)] = __floats2half2_rn(w0, w1);
    }
    __syncthreads();
    int wid = tid >> 6, lane = tid & 63;
    int col = lane & 15, quad = lane >> 4;
    int m_a = m0 + wid * 16 + col;
    bool a_ok = m_a < M;
    constexpr int NT = N / 16;
    floatx4 acc[NT] = {};
#pragma unroll
    for (int ks = 0; ks < 4; ++ks) {
        int k = ks * 32 + quad * 8;
        half8 af;
        if constexpr (sizeof(AT) == 4) {
            floatx4 a0 = {0.f, 0.f, 0.f, 0.f}, a1 = {0.f, 0.f, 0.f, 0.f};
            if (a_ok) {
                a0 = *(const floatx4*)&X[(size_t)m_a * 128 + k];
                a1 = *(const floatx4*)&X[(size_t)m_a * 128 + k + 4];
            }
            af = half8{(_Float16)a0[0], (_Float16)a0[1], (_Float16)a0[2], (_Float16)a0[3],
                       (_Float16)a1[0], (_Float16)a1[1], (_Float16)a1[2], (_Float16)a1[3]};
        } else {
            half8 t = {};
            if (a_ok) t = *(const half8*)(const void*)&X[(size_t)m_a * 128 + k];
            af = t;
        }
        int kblk = ks * 4 + quad;
#pragma unroll
        for (int nt = 0; nt < NT; ++nt) {
            int nn = nt * 16 + col;
            half8 bf = *(const half8*)(const void*)&wt[nn * 64 + (kblk ^ (nn & 15)) * 4];
            acc[nt] = __builtin_amdgcn_mfma_f32_16x16x32_f16(af, bf, acc[nt], 0, 0, 0);
        }
    }
    int mbase = m0 + wid * 16 + quad * 4;
    float s[4];
#pragma unroll
    for (int r = 0; r < 4; ++r) s[r] = (mbase + r < M) ? scale[mbase + r] : 0.f;
#pragma unroll
    for (int nt = 0; nt < NT; ++nt) {
#pragma unroll
        for (int r = 0; r < 4; ++r) {
            if (mbase + r < M)
                Y[(size_t)(mbase + r) * N + nt * 16 + col] = __float2half(acc[nt][r] * s[r]);
        }
    }
}

// Fused 3-range kernel:
//   blocks [0,FB):        scan_fix — add chunk prefix to rowptr (for aggs)
//   blocks [FB,FB+GB):    gemm1 (MFMA)
//   blocks [FB+GB,...):   CSR fill — pos = praw[c] + Q[(c-1)>>10] + rank[e],
//                         Q scanned from bsum in LDS (no dep on fix; praw is
//                         a separate copy so concurrent fix can't race).
__global__ __launch_bounds__(256) void k_fused(int* __restrict__ rowptr,
                                               const int* __restrict__ bsum, int n,
                                               const float* __restrict__ X,
                                               const float* __restrict__ W,
                                               const float* __restrict__ scale,
                                               __half* __restrict__ Y, int M,
                                               int FB, int GB,
                                               const int* __restrict__ praw,
                                               const int* __restrict__ row,
                                               const int* __restrict__ col,
                                               const int* __restrict__ rank,
                                               int* __restrict__ csr, int E) {
    __shared__ __align__(16) __half2 wt[128 * 64];  // 32 KB (gemm); reused by fix/fill
    int b = blockIdx.x, tid = threadIdx.x;
    if (b < FB) {
        int* red = (int*)wt;
        int partial = 0;
        for (int j = tid; j < b; j += 256) partial += bsum[j];
        red[tid] = partial;
        __syncthreads();
        for (int off = 128; off > 0; off >>= 1) {
            if (tid < off) red[tid] += red[tid + off];
            __syncthreads();
        }
        int offv = red[0];
        if (offv == 0) return;
#pragma unroll
        for (int r = 0; r < 4; ++r) {
            int i = b * 1024 + r * 256 + tid;
            if (i < n) rowptr[i + 1] += offv;
        }
        return;
    }
    if (b >= FB + GB) {
        // ---- fill range: 1024 edges per block ----
        int* q = (int*)wt;  // Q[l] = sum bsum[0..l-1], l in [0,63]
        int nb = (n + 1023) >> 10;  // chunk count (<=49 here, <=64 supported)
        if (tid < 64) {
            int v = (tid >= 1 && tid <= nb) ? bsum[tid - 1] : 0;
#pragma unroll
            for (int off = 1; off < 64; off <<= 1) {
                int t = __shfl_up(v, off);
                if ((tid & 63) >= off) v += t;
            }
            q[tid] = v;  // inclusive scan of shifted bsum == exclusive prefix Q
        }
        __syncthreads();
        int base = (b - FB - GB) * 1024;
#pragma unroll
        for (int r = 0; r < 4; ++r) {
            int e = base + r * 256 + tid;
            if (e < E) {
                int c = col[e];
                int qi = (c == 0) ? 0 : ((c - 1) >> 10);  // praw[0]=0, Q[0]=0
                csr[praw[c] + q[qi] + rank[e]] = row[e];
            }
        }
        return;
    }
    gemm_tile<128, float>(X, W, scale, Y, M, (b - FB) * 64, wt, tid);
}

// Fused agg128 + gemm2. Block = 64 nodes (4 agg sub-phases of 16 nodes),
// then xw2[64,64] = (h_tile @ W2) * dis via MFMA.
// Agg: 4 nodes/wave (quad per node; 16 lanes x 16B = one 256B row per
// gather instr), cooperative csr load (1 VMEM / 8 edges, shfl spread),
// csr index load SOFTWARE-PIPELINED one iteration ahead (r19).
// h_tile row m stored in LDS with 16B-slot XOR swizzle slot^=(m&7).
__global__ __launch_bounds__(256) void k_agg_gemm(const __half* __restrict__ xw,
                                                  const float* __restrict__ dis,
                                                  const int* __restrict__ rowptr,
                                                  const int* __restrict__ csr,
                                                  const float* __restrict__ bias,
                                                  const float* __restrict__ W2,
                                                  __half* __restrict__ Y,  // xw2 [n,64]
                                                  int n) {
    __shared__ __align__(16) half8 htile[64 * 16];   // 16 KB
    __shared__ __align__(16) __half2 wt[64 * 64];    // 16 KB
    int tid = threadIdx.x, b = blockIdx.x;
    int lane = tid & 63, w = tid >> 6;
    int q = lane >> 4, li = lane & 15;
    int qbase = lane & 48;

    // Stage W2 -> LDS (overlaps the first agg phase's latency).
    for (int i = tid; i < 64 * 64; i += 256) {
        int nn = i & 63;
        int k2 = i >> 6;  // k = 2*k2
        float w0 = W2[(size_t)(2 * k2) * 64 + nn];
        float w1 = W2[(size_t)(2 * k2 + 1) * 64 + nn];
        wt[nn * 64 + ((k2 >> 2) ^ (nn & 15)) * 4 + (k2 & 3)] = __floats2half2_rn(w0, w1);
    }

    const half8* rows = (const half8*)xw;  // 16 half8 per row
    floatx4 bb0 = *(const floatx4*)&bias[li * 8];
    floatx4 bb1 = *(const floatx4*)&bias[li * 8 + 4];

#pragma unroll
    for (int g = 0; g < 4; ++g) {
        int m_loc = g * 16 + (w << 2) + q;     // local row 0..63
        int node = b * 64 + m_loc;
        bool ok = node < n;
        float di = 0.f;
        int beg = 0, end = 0;
        if (ok) {
            di = dis[node];
            beg = rowptr[node];
            end = rowptr[node + 1];
        }
        int dg = end - beg;
        int m1 = max(dg, __shfl(dg, lane ^ 16));
        int mx = max(m1, __shfl(m1, lane ^ 32));  // max over the wave's 4 nodes
        float acc[8] = {};
        if (ok) {
            half8 sf = rows[(size_t)node * 16 + li];
#pragma unroll
            for (int f = 0; f < 8; ++f) acc[f] = (float)sf[f];
        }
        // software-pipelined csr index load (one iteration ahead)
        int ecur = beg + (li & 7);
        int curidx = (0 < mx && ecur < end) ? csr[ecur] : 0;
        for (int i = 0; i < mx; i += 8) {
            int enx = beg + i + 8 + (li & 7);
            int nidx = (i + 8 < mx && enx < end) ? csr[enx] : 0;
            half8 v[8];
#pragma unroll
            for (int j = 0; j < 8; ++j) {
                int s = __shfl(curidx, qbase + j);
                v[j] = rows[(size_t)s * 16 + li];
            }
#pragma unroll
            for (int j = 0; j < 8; ++j) {
                if (beg + i + j < end) {
#pragma unroll
                    for (int f = 0; f < 8; ++f) acc[f] += (float)v[j][f];
                }
            }
            curidx = nidx;
        }
        half8 o = {};
        if (ok) {
#pragma unroll
            for (int f = 0; f < 4; ++f) o[f] = (_Float16)fmaxf(acc[f] * di + bb0[f], 0.f);
#pragma unroll
            for (int f = 0; f < 4; ++f) o[4 + f] = (_Float16)fmaxf(acc[4 + f] * di + bb1[f], 0.f);
        }
        htile[m_loc * 16 + (li ^ (m_loc & 7))] = o;
    }
    __syncthreads();

    // GEMM phase: A from htile (swizzled), B from wt.
    int col16 = lane & 15, quad = lane >> 4;
    int m_loc = w * 16 + col16;
    floatx4 gacc[4] = {};
#pragma unroll
    for (int ks = 0; ks < 4; ++ks) {
        half8 af = htile[m_loc * 16 + ((ks * 4 + quad) ^ (m_loc & 7))];
        int kblk = ks * 4 + quad;
#pragma unroll
        for (int nt = 0; nt < 4; ++nt) {
            int nn = nt * 16 + col16;
            half8 bf = *(const half8*)(const void*)&wt[nn * 64 + (kblk ^ (nn & 15)) * 4];
            gacc[nt] = __builtin_amdgcn_mfma_f32_16x16x32_f16(af, bf, gacc[nt], 0, 0, 0);
        }
    }
    int mbase = b * 64 + w * 16 + quad * 4;
    float s[4];
#pragma unroll
    for (int r = 0; r < 4; ++r) s[r] = (mbase + r < n) ? dis[mbase + r] : 0.f;
#pragma unroll
    for (int nt = 0; nt < 4; ++nt) {
#pragma unroll
        for (int r = 0; r < 4; ++r) {
            if (mbase + r < n)
                Y[(size_t)(mbase + r) * 64 + nt * 16 + col16] = __float2half(gacc[nt][r] * s[r]);
        }
    }
}

// F=64: 8 nodes/wave (8 lanes x 16B = one 128B row per gather instr).
// csr index load software-pipelined one iteration ahead (r19).
__global__ __launch_bounds__(256) void k_agg64(const __half* __restrict__ xw,
                                               const float* __restrict__ dis,
                                               const int* __restrict__ rowptr,
                                               const int* __restrict__ csr,
                                               const float* __restrict__ bias,
                                               float* __restrict__ out, int n) {
    int tid = threadIdx.x;
    int lane = tid & 63;
    int o8 = lane >> 3, li = lane & 7;
    int obase = lane & 56;
    int node = blockIdx.x * 32 + ((tid >> 6) << 3) + o8;
    bool ok = node < n;
    float di = 0.f;
    int beg = 0, end = 0;
    if (ok) {
        di = dis[node];
        beg = rowptr[node];
        end = rowptr[node + 1];
    }
    int dg = end - beg;
    int m1 = max(dg, __shfl(dg, lane ^ 8));
    int m2 = max(m1, __shfl(m1, lane ^ 16));
    int mx = max(m2, __shfl(m2, lane ^ 32));  // max over the wave's 8 nodes
    const half8* rows = (const half8*)xw;     // 8 half8 per row
    float acc[8] = {};
    if (ok) {
        half8 sf = rows[(size_t)node * 8 + li];
#pragma unroll
        for (int f = 0; f < 8; ++f) acc[f] = (float)sf[f];
    }
    int ecur = beg + li;
    int curidx = (0 < mx && ecur < end) ? csr[ecur] : 0;
    for (int i = 0; i < mx; i += 8) {
        int enx = beg + i + 8 + li;
        int nidx = (i + 8 < mx && enx < end) ? csr[enx] : 0;
        half8 v[8];
#pragma unroll
        for (int j = 0; j < 8; ++j) {
            int s = __shfl(curidx, obase + j);
            v[j] = rows[(size_t)s * 8 + li];
        }
#pragma unroll
        for (int j = 0; j < 8; ++j) {
            if (beg + i + j < end) {
#pragma unroll
                for (int f = 0; f < 8; ++f) acc[f] += (float)v[j][f];
            }
        }
        curidx = nidx;
    }
    if (ok) {
        floatx4 b0 = *(const floatx4*)&bias[li * 8];
        floatx4 b1 = *(const floatx4*)&bias[li * 8 + 4];
        floatx4 o0, o1;
#pragma unroll
        for (int f = 0; f < 4; ++f) o0[f] = acc[f] * di + b0[f];
#pragma unroll
        for (int f = 0; f < 4; ++f) o1[f] = acc[4 + f] * di + b1[f];
        *(floatx4*)&out[(size_t)node * 64 + li * 8] = o0;
        *(floatx4*)&out[(size_t)node * 64 + li * 8 + 4] = o1;
    }
}

extern "C" void kernel_launch(void* const* d_in, const int* in_sizes, int n_in,
                              void* d_out, int out_size, void* d_ws, size_t ws_size,
                              hipStream_t stream) {
    const float* x  = (const float*)d_in[0];
    const int*   ei = (const int*)d_in[1];
    const float* W1 = (const float*)d_in[2];
    const float* b1 = (const float*)d_in[3];
    const float* W2 = (const float*)d_in[4];
    const float* b2 = (const float*)d_in[5];
    float* out = (float*)d_out;

    const int n = in_sizes[0] / 128;   // 50000
    const int E = in_sizes[1] / 2;     // 800000
    const int* row = ei;
    const int* col = ei + E;
    const int NB = (n + 1023) / 1024;       // scan chunks (fix range)
    const int CB = (E + 255) / 256;
    const int GB = (n + 63) / 64;           // gemm1 / agg_gemm blocks
    const int FILLB = (E + 1023) / 1024;    // fused fill blocks (1024 edges each)

    char* ws = (char*)d_ws;
    size_t off = 0;
    auto alloc = [&](size_t bytes) -> void* {
        void* p = ws + off;
        off += (bytes + 255) & ~(size_t)255;
        return p;
    };
    int*    deg    = (int*)alloc((size_t)n * 4);
    int*    rowptr = (int*)alloc((size_t)(n + 1) * 4);
    int*    praw   = (int*)alloc((size_t)(n + 1) * 4);
    int*    bsum   = (int*)alloc((size_t)NB * 4);
    int*    rank   = (int*)alloc((size_t)E * 4);
    int*    csr    = (int*)alloc((size_t)E * 4);
    float*  dis    = (float*)alloc((size_t)n * 4);
    __half* xw1    = (__half*)alloc((size_t)n * 128 * 2);
    __half* xw2    = (__half*)alloc((size_t)n * 64 * 2);
    (void)ws_size;

    hipMemsetAsync(deg, 0, (size_t)n * 4, stream);
    k_count<<<CB, 256, 0, stream>>>(col, deg, rank, E);
    k_scan_local<<<NB, 1024, 0, stream>>>(deg, rowptr, praw, bsum, dis, n);
    // fix || gemm1 || fill in one dispatch (independent resources; fill uses
    // praw + per-block bsum-prefix so it never reads the rowptr fix mutates).
    k_fused<<<NB + GB + FILLB, 256, 0, stream>>>(rowptr, bsum, n, x, W1, dis, xw1,
                                                 n, NB, GB, praw, row, col, rank,
                                                 csr, E);
    // agg128 + gemm2 fused: h never touches HBM.
    k_agg_gemm<<<GB, 256, 0, stream>>>(xw1, dis, rowptr, csr, b1, W2, xw2, n);
    k_agg64<<<(n + 31) / 32, 256, 0, stream>>>(xw2, dis, rowptr, csr, b2, out, n);
}